// Round 1
// baseline (29.129 us; speedup 1.0000x reference)
//
#include <hip/hip_runtime.h>

// Problem constants (from reference): feat (32, 64, 112, 112) fp32
#define BB 32
#define CC 64
#define HH 112
#define WW 112
#define HW (HH * WW)          // 12544
#define KS 14
#define HP (HH - KS + 1)      // 99
#define WP (WW - KS + 1)      // 99

// Kernel 1: s2[b,h,w] = (sum_c feat[b,c,h,w])^2, float4-vectorized over (h,w).
__global__ __launch_bounds__(256) void chan_sum_sq(const float* __restrict__ feat,
                                                   float* __restrict__ s2) {
    const int n4 = BB * (HW / 4);
    int idx4 = blockIdx.x * blockDim.x + threadIdx.x;
    if (idx4 >= n4) return;
    int b = idx4 / (HW / 4);
    int r = idx4 % (HW / 4);
    const float4* base =
        reinterpret_cast<const float4*>(feat) + (size_t)b * CC * (HW / 4) + r;
    float4 acc = make_float4(0.f, 0.f, 0.f, 0.f);
#pragma unroll 8
    for (int c = 0; c < CC; ++c) {
        float4 v = base[(size_t)c * (HW / 4)];
        acc.x += v.x; acc.y += v.y; acc.z += v.z; acc.w += v.w;
    }
    float4 o;
    o.x = acc.x * acc.x;
    o.y = acc.y * acc.y;
    o.z = acc.z * acc.z;
    o.w = acc.w * acc.w;
    reinterpret_cast<float4*>(s2)[idx4] = o;
}

// Kernel 2: horizontal 14-tap sums. tmp[b,h,wp] = sum_k s2[b,h,wp+k]
__global__ __launch_bounds__(256) void hwin(const float* __restrict__ s2,
                                            float* __restrict__ tmp) {
    const int n = BB * HH * WP;
    int i = blockIdx.x * blockDim.x + threadIdx.x;
    if (i >= n) return;
    int wp = i % WP;
    int t = i / WP;
    int h = t % HH;
    int b = t / HH;
    const float* row = s2 + ((size_t)b * HH + h) * WW + wp;
    float s = 0.f;
#pragma unroll
    for (int k = 0; k < KS; ++k) s += row[k];
    tmp[i] = s;
}

// Kernel 3: vertical 14-tap sums * 1/196. pooled[b,hp,wp]
__global__ __launch_bounds__(256) void vwin(const float* __restrict__ tmp,
                                            float* __restrict__ pooled) {
    const int n = BB * HP * WP;
    int i = blockIdx.x * blockDim.x + threadIdx.x;
    if (i >= n) return;
    int wp = i % WP;
    int t = i / WP;
    int hp = t % HP;
    int b = t / HP;
    const float* col = tmp + ((size_t)b * HH + hp) * WP + wp;
    float s = 0.f;
#pragma unroll
    for (int k = 0; k < KS; ++k) s += col[(size_t)k * WP];
    pooled[i] = s * (1.f / (float)(KS * KS));
}

// Kernel 4: sim = C^2 * pooled * (sum of 8 neighbors, zero-padded)
__global__ __launch_bounds__(256) void simk(const float* __restrict__ pooled,
                                            float* __restrict__ out) {
    const int n = BB * HP * WP;
    int i = blockIdx.x * blockDim.x + threadIdx.x;
    if (i >= n) return;
    int wp = i % WP;
    int t = i / WP;
    int hp = t % HP;
    int b = t / HP;
    const float* pb = pooled + (size_t)b * HP * WP;
    float center = pb[hp * WP + wp];
    float ns = 0.f;
#pragma unroll
    for (int dy = -1; dy <= 1; ++dy) {
#pragma unroll
        for (int dx = -1; dx <= 1; ++dx) {
            if (dy == 0 && dx == 0) continue;
            int y = hp + dy, x = wp + dx;
            if (y >= 0 && y < HP && x >= 0 && x < WP) {
                ns += pb[y * WP + x];
            }
        }
    }
    out[i] = (float)(CC * CC) * center * ns;
}

extern "C" void kernel_launch(void* const* d_in, const int* in_sizes, int n_in,
                              void* d_out, int out_size, void* d_ws, size_t ws_size,
                              hipStream_t stream) {
    const float* feat = (const float*)d_in[0];
    float* out = (float*)d_out;

    // Workspace layout (floats):
    //   s2:     BB*HW          = 401,408
    //   tmp:    BB*HH*WP       = 354,816
    //   pooled: BB*HP*WP       = 313,632
    float* s2 = (float*)d_ws;
    float* tmp = s2 + (size_t)BB * HW;
    float* pooled = tmp + (size_t)BB * HH * WP;

    {
        int n4 = BB * (HW / 4);
        int blk = 256;
        chan_sum_sq<<<(n4 + blk - 1) / blk, blk, 0, stream>>>(feat, s2);
    }
    {
        int n = BB * HH * WP;
        int blk = 256;
        hwin<<<(n + blk - 1) / blk, blk, 0, stream>>>(s2, tmp);
    }
    {
        int n = BB * HP * WP;
        int blk = 256;
        vwin<<<(n + blk - 1) / blk, blk, 0, stream>>>(tmp, pooled);
    }
    {
        int n = BB * HP * WP;
        int blk = 256;
        simk<<<(n + blk - 1) / blk, blk, 0, stream>>>(pooled, out);
    }
}